// Round 6
// baseline (231.879 us; speedup 1.0000x reference)
//
#include <hip/hip_runtime.h>
#include <hip/hip_cooperative_groups.h>

namespace cg = cooperative_groups;

#define DM 512
#define DI 1024
#define MM 16

typedef __attribute__((ext_vector_type(4))) float f32x4;
typedef __attribute__((ext_vector_type(8))) short short8;
typedef __attribute__((ext_vector_type(8))) unsigned short ushort8;

__device__ __forceinline__ unsigned short f2bf(float x) {
  union { float f; unsigned u; } c; c.f = x;
  unsigned r = (c.u + 0x7fffu + ((c.u >> 16) & 1u)) >> 16;
  return (unsigned short)r;
}

__device__ __forceinline__ void gload_lds16(const void* g, void* l) {
  __builtin_amdgcn_global_load_lds(
      (const __attribute__((address_space(1))) unsigned int*)g,
      (__attribute__((address_space(3))) unsigned int*)l, 16, 0, 0);
}

// ================= G1/G2 body: 256x128 tile, BK=64, 8 waves (2Mx4N),
// 2-phase/K-tile, counted vmcnt ledger, T2 swizzle (R5-proven, verbatim).
#define ST_A(BASE, KT, CH)                                                    \
  gload_lds16(Ab + (size_t)((CH)*64 + strow) * 1024 + ((KT)<<6) + stcolh,     \
              smem + (BASE) + (CH)*8192 + t*16);
#define ST_B(BASE, KT, CB)                                                    \
  gload_lds16(Bb + (size_t)((CB)*64 + strow) * 1024 + ((KT)<<6) + stcolh,     \
              smem + (BASE) + 32768 + (CB)*8192 + t*16);
#define ST_QM0B(BASE, KT) { ST_A(BASE,KT,0) ST_A(BASE,KT,2) ST_B(BASE,KT,0) ST_B(BASE,KT,1) }
#define ST_QM1(BASE, KT)  { ST_A(BASE,KT,1) ST_A(BASE,KT,3) }
#define WAIT_VM(N) { asm volatile("s_waitcnt vmcnt(" #N ")" ::: "memory");    \
                     __builtin_amdgcn_sched_barrier(0); }
#define WAIT_LGKM() { asm volatile("s_waitcnt lgkmcnt(0)" ::: "memory");      \
                      __builtin_amdgcn_sched_barrier(0); }
#define BAR() { __builtin_amdgcn_s_barrier();                                 \
                __builtin_amdgcn_sched_barrier(0); }
#define LDA(MF4, KK, BASE, QM)                                                \
  aF[MF4][KK] = *(const short8*)(smem + (BASE) +                              \
      ((((wr*128 + ((QM)*4+(MF4))*16 + r) * 128) + ((KK)*32 + ko)*2) ^ swz));
#define LDB(NF, KK, BASE)                                                     \
  bF[NF][KK] = *(const short8*)(smem + (BASE) + 32768 +                       \
      ((((wc*32 + (NF)*16 + r) * 128) + ((KK)*32 + ko)*2) ^ swz));
#define MFMA16(QM)                                                            \
  __builtin_amdgcn_s_setprio(1);                                              \
  _Pragma("unroll") for (int mf4 = 0; mf4 < 4; ++mf4)                         \
    _Pragma("unroll") for (int kk = 0; kk < 2; ++kk)                          \
      _Pragma("unroll") for (int nf = 0; nf < 2; ++nf)                        \
        acc[(QM)*4+mf4][nf] = __builtin_amdgcn_mfma_f32_16x16x32_bf16(        \
            aF[mf4][kk], bF[nf][kk], acc[(QM)*4+mf4][nf], 0, 0, 0);           \
  __builtin_amdgcn_s_setprio(0);
#define DS_A(BASE, QM) _Pragma("unroll")                                      \
  for (int mf4 = 0; mf4 < 4; ++mf4) { LDA(mf4,0,BASE,QM) LDA(mf4,1,BASE,QM) }
#define DS_B(BASE) { LDB(0,0,BASE) LDB(0,1,BASE) LDB(1,0,BASE) LDB(1,1,BASE) }

__device__ __forceinline__ void gemm256_body(char* smem, int t, int f,
    const unsigned short* __restrict__ A, const unsigned short* __restrict__ Bt,
    const float* __restrict__ bias, unsigned short* __restrict__ C) {
  const int l = t & 63, w = t >> 6;
  const int wr = w >> 2, wc = w & 3;            // 2M x 4N waves
  const int swzid = (f & 7) * 32 + (f >> 3);    // chunked XCD swizzle
  const int bx = swzid & 7, by = swzid >> 3;
  const int blockM = by * 256, blockN = bx * 128;
  const unsigned short* __restrict__ Ab = A + (size_t)blockM * 1024;
  const unsigned short* __restrict__ Bb = Bt + (size_t)blockN * 1024;
  const int r = l & 15, ko = (l >> 4) * 8;
  const int swz = (r & 7) << 4;
  const int strow = t >> 3;
  const int stcolh = ((((t & 7) * 16) ^ ((strow & 7) << 4)) >> 1);

  f32x4 acc[8][2];
  #pragma unroll
  for (int m = 0; m < 8; ++m) {
    acc[m][0] = (f32x4){0.f,0.f,0.f,0.f};
    acc[m][1] = (f32x4){0.f,0.f,0.f,0.f};
  }
  short8 aF[4][2], bF[2][2];

  // prologue: tiles 0,1 fully staged (12 loads; oldest 4 = t0 qm0+B)
  ST_QM0B(0, 0) ST_QM1(0, 0)
  ST_QM0B(49152, 1) ST_QM1(49152, 1)
  WAIT_VM(8) BAR()
  // G(0)
  { DS_A(0,0) DS_B(0)
    WAIT_LGKM() MFMA16(0)
    WAIT_VM(6) BAR() }
  { DS_A(0,1)
    ST_QM0B(0, 2)
    WAIT_LGKM() MFMA16(1)
    WAIT_VM(6) BAR() }
  // steady kt = 1..13
  #pragma unroll 1
  for (int kt = 1; kt <= 13; ++kt) {
    const int bo = (kt & 1) * 49152;
    const int bo2 = bo ^ 49152;
    { DS_A(bo,0) DS_B(bo)
      ST_QM1(bo2, kt+1)
      WAIT_LGKM() MFMA16(0)
      WAIT_VM(6) BAR() }
    { DS_A(bo,1)
      ST_QM0B(bo, kt+2)
      WAIT_LGKM() MFMA16(1)
      WAIT_VM(6) BAR() }
  }
  // G(14) (buf0)
  { DS_A(0,0) DS_B(0)
    ST_QM1(49152, 15)
    WAIT_LGKM() MFMA16(0)
    WAIT_VM(6) BAR() }
  { DS_A(0,1)
    WAIT_LGKM() MFMA16(1)
    WAIT_VM(2) BAR() }
  // G(15) (buf1)
  { DS_A(49152,0) DS_B(49152)
    WAIT_LGKM() MFMA16(0)
    WAIT_VM(0) BAR() }
  { DS_A(49152,1)
    WAIT_LGKM() MFMA16(1) }

  float bn2[2];
  bn2[0] = bias[blockN + wc * 32 + r];
  bn2[1] = bias[blockN + wc * 32 + 16 + r];
  const int rowBase = blockM + wr * 128 + (l >> 4) * 4;
  #pragma unroll
  for (int mf = 0; mf < 8; ++mf)
    #pragma unroll
    for (int j = 0; j < 4; ++j) {
      int grow = rowBase + mf * 16 + j;
      #pragma unroll
      for (int nf = 0; nf < 2; ++nf) {
        float v = acc[mf][nf][j] + bn2[nf];
        v = v > 0.f ? v : 0.f;
        C[(size_t)grow * 1024 + blockN + wc * 32 + nf * 16 + r] = f2bf(v);
      }
    }
}

#undef ST_A
#undef ST_B
#undef ST_QM0B
#undef ST_QM1
#undef WAIT_VM
#undef WAIT_LGKM
#undef BAR
#undef LDA
#undef LDB
#undef MFMA16
#undef DS_A
#undef DS_B

// ================= G3 body: 128x128 tile, 512 threads, 8 waves (2Mx4N),
// m97 single-buffer 2-barrier schedule (compiler-managed waits), counts
// mask, f32 out. Grid must be 256 blocks. LDS 32 KB.
__device__ __forceinline__ void gemm128f_body(char* smem, int t, int f,
    const unsigned short* __restrict__ A, const unsigned short* __restrict__ Bt,
    const float* __restrict__ bias, const int* __restrict__ counts,
    float* __restrict__ Out) {
  const int l = t & 63, w = t >> 6;
  const int wr = w >> 2, wc = w & 3;           // 2M x 4N
  const int swzid = (f & 7) * 32 + (f >> 3);
  const int bx = swzid & 3, by = swzid >> 2;   // 4 N-blocks, 64 M-blocks
  const int blockM = by * 128, blockN = bx * 128;
  const unsigned short* __restrict__ Ab = A + (size_t)blockM * 1024;
  const unsigned short* __restrict__ Bb = Bt + (size_t)blockN * 1024;
  const int r = l & 15, ko = (l >> 4) * 8;
  const int swz = (r & 7) << 4;

  int srow[2], scolh[2];
  #pragma unroll
  for (int c = 0; c < 2; ++c) {
    int o = c * 8192 + t * 16;
    int row = o >> 7;
    int cb = (o & 127) ^ ((row & 7) << 4);
    srow[c] = row; scolh[c] = cb >> 1;
  }
  f32x4 acc[4][2];
  #pragma unroll
  for (int m = 0; m < 4; ++m) {
    acc[m][0] = (f32x4){0.f,0.f,0.f,0.f};
    acc[m][1] = (f32x4){0.f,0.f,0.f,0.f};
  }
  #pragma unroll
  for (int c = 0; c < 2; ++c) {
    gload_lds16(Ab + (size_t)srow[c] * 1024 + scolh[c], smem + c * 8192 + t * 16);
    gload_lds16(Bb + (size_t)srow[c] * 1024 + scolh[c], smem + 16384 + c * 8192 + t * 16);
  }
  for (int kt = 0; kt < 16; ++kt) {
    __syncthreads();
    short8 aF[4][2], bF[2][2];
    #pragma unroll
    for (int kk = 0; kk < 2; ++kk) {
      #pragma unroll
      for (int mf = 0; mf < 4; ++mf)
        aF[mf][kk] = *(const short8*)(smem + (((wr*64 + mf*16 + r) * 128 + (kk*32 + ko)*2) ^ swz));
      #pragma unroll
      for (int nf = 0; nf < 2; ++nf)
        bF[nf][kk] = *(const short8*)(smem + 16384 + (((wc*32 + nf*16 + r) * 128 + (kk*32 + ko)*2) ^ swz));
    }
    #pragma unroll
    for (int kk = 0; kk < 2; ++kk)
      #pragma unroll
      for (int mf = 0; mf < 4; ++mf)
        #pragma unroll
        for (int nf = 0; nf < 2; ++nf)
          acc[mf][nf] = __builtin_amdgcn_mfma_f32_16x16x32_bf16(aF[mf][kk], bF[nf][kk], acc[mf][nf], 0, 0, 0);
    __syncthreads();
    if (kt < 15) {
      int k0 = (kt + 1) << 6;
      #pragma unroll
      for (int c = 0; c < 2; ++c) {
        gload_lds16(Ab + (size_t)srow[c] * 1024 + k0 + scolh[c], smem + c * 8192 + t * 16);
        gload_lds16(Bb + (size_t)srow[c] * 1024 + k0 + scolh[c], smem + 16384 + c * 8192 + t * 16);
      }
    }
  }
  float bn2[2];
  bn2[0] = bias[blockN + wc * 32 + r];
  bn2[1] = bias[blockN + wc * 32 + 16 + r];
  const int rowBase = blockM + wr * 64 + (l >> 4) * 4;
  #pragma unroll
  for (int mf = 0; mf < 4; ++mf)
    #pragma unroll
    for (int j = 0; j < 4; ++j) {
      int grow = rowBase + mf * 16 + j;
      float cm = (counts[grow] > 0) ? 1.0f : 0.0f;
      #pragma unroll
      for (int nf = 0; nf < 2; ++nf)
        Out[(size_t)grow * 512 + blockN + wc * 32 + nf * 16 + r] =
            (acc[mf][nf][j] + bn2[nf]) * cm;
    }
}

// ================= prep helpers
__device__ __forceinline__ void gather_row(const float* __restrict__ Aemb,
                                           const float* __restrict__ Bemb,
                                           const int* __restrict__ midx,
                                           unsigned short* __restrict__ X,
                                           int* __restrict__ counts,
                                           int row, int l) {
  float acc[8] = {0,0,0,0,0,0,0,0};
  int cnt = 0;
  const int* ip = midx + row * MM;
  #pragma unroll
  for (int m = 0; m < MM; ++m) {
    int id = ip[m];
    if (id >= 0) {
      ++cnt;
      const f32x4* p = (const f32x4*)(Bemb + (size_t)id * DM) + l * 2;
      f32x4 u = p[0], v = p[1];
      acc[0]+=u[0]; acc[1]+=u[1]; acc[2]+=u[2]; acc[3]+=u[3];
      acc[4]+=v[0]; acc[5]+=v[1]; acc[6]+=v[2]; acc[7]+=v[3];
    }
  }
  float inv = 1.0f / (float)(cnt > 0 ? cnt : 1);
  const f32x4* pa = (const f32x4*)(Aemb + (size_t)row * DM) + l * 2;
  f32x4 a0 = pa[0], a1 = pa[1];
  ushort8 va, vb;
  va[0]=f2bf(a0[0]); va[1]=f2bf(a0[1]); va[2]=f2bf(a0[2]); va[3]=f2bf(a0[3]);
  va[4]=f2bf(a1[0]); va[5]=f2bf(a1[1]); va[6]=f2bf(a1[2]); va[7]=f2bf(a1[3]);
  #pragma unroll
  for (int i = 0; i < 8; ++i) vb[i] = f2bf(acc[i] * inv);
  *(ushort8*)(X + (size_t)row * DI + l * 8) = va;
  *(ushort8*)(X + (size_t)row * DI + DM + l * 8) = vb;
  if (l == 0) counts[row] = cnt;
}

// ================= mega cooperative kernel: prep -> G1 -> G2 -> G3
__global__ __launch_bounds__(512, 2)
void mega_kernel(const float* __restrict__ Aemb, const float* __restrict__ Bemb,
                 const int* __restrict__ midx,
                 const float* __restrict__ W_in, const float* __restrict__ W_h,
                 const float* __restrict__ W_out,
                 const float* __restrict__ b_in, const float* __restrict__ b_h,
                 const float* __restrict__ b_out,
                 unsigned short* __restrict__ X, unsigned short* __restrict__ H1,
                 unsigned short* __restrict__ Wt_in, unsigned short* __restrict__ Wt_h,
                 unsigned short* __restrict__ Wt_out,
                 int* __restrict__ counts, float* __restrict__ Out) {
  extern __shared__ __align__(16) char smem[];
  const int t = threadIdx.x;
  const int blk = blockIdx.x;           // grid = 256 x 1

  // ---- prep: 10 weight-transpose tiles per block
  {
    float (*ftile)[33] = (float(*)[33])smem;
    const int tx = t & 31, ty = t >> 5;   // ty 0..15
    #pragma unroll 1
    for (int i = 0; i < 10; ++i) {
      int T = blk * 10 + i;
      const float* W; unsigned short* Wt; int N, bxx, byy;
      if (T < 1024)      { W = W_in;  Wt = Wt_in;  N = 1024; bxx = (T & 31) * 32;  byy = (T >> 5) * 32; }
      else if (T < 2048) { int lb = T - 1024; W = W_h;  Wt = Wt_h;  N = 1024; bxx = (lb & 31) * 32; byy = (lb >> 5) * 32; }
      else               { int lb = T - 2048; W = W_out; Wt = Wt_out; N = 512; bxx = (lb & 15) * 32; byy = (lb >> 4) * 32; }
      #pragma unroll
      for (int i2 = ty; i2 < 32; i2 += 16)
        ftile[i2][tx] = W[(size_t)(byy + i2) * N + bxx + tx];
      __syncthreads();
      #pragma unroll
      for (int i2 = ty; i2 < 32; i2 += 16)
        Wt[(size_t)(bxx + i2) * 1024 + byy + tx] = f2bf(ftile[tx][i2]);
      __syncthreads();
    }
  }
  // ---- prep: gather, 32 rows/block (8 waves x 4 rows)
  {
    const int w8 = t >> 6, l = t & 63;
    #pragma unroll 1
    for (int q = 0; q < 4; ++q)
      gather_row(Aemb, Bemb, midx, X, counts, blk * 32 + w8 * 4 + q, l);
  }

  cg::this_grid().sync();
  gemm256_body(smem, t, blk, X, Wt_in, b_in, H1);
  cg::this_grid().sync();
  gemm256_body(smem, t, blk, H1, Wt_h, b_h, X);
  cg::this_grid().sync();
  gemm128f_body(smem, t, blk, X, Wt_out, b_out, counts, Out);
}

// ================= fallback path (R5-proven function, separate launches)
__global__ __launch_bounds__(256)
void prep_kernel(const float* __restrict__ Aemb,
                 const float* __restrict__ Bemb,
                 const int* __restrict__ midx,
                 const float* __restrict__ W_in,
                 const float* __restrict__ W_h,
                 const float* __restrict__ W_out,
                 unsigned short* __restrict__ X,
                 int* __restrict__ counts,
                 unsigned short* __restrict__ Wt_in,
                 unsigned short* __restrict__ Wt_h,
                 unsigned short* __restrict__ Wt_out) {
  __shared__ float tile[32][33];
  const int b = blockIdx.x;
  const int tx = threadIdx.x & 31, ty = threadIdx.x >> 5;
  if (b < 2560) {
    const float* W; unsigned short* Wt; int N, bxx, byy;
    if (b < 1024)      { W = W_in;  Wt = Wt_in;  N = 1024; bxx = (b & 31) * 32;  byy = (b >> 5) * 32; }
    else if (b < 2048) { int lb = b - 1024; W = W_h;  Wt = Wt_h;  N = 1024; bxx = (lb & 31) * 32; byy = (lb >> 5) * 32; }
    else               { int lb = b - 2048; W = W_out; Wt = Wt_out; N = 512; bxx = (lb & 15) * 32; byy = (lb >> 4) * 32; }
    #pragma unroll
    for (int i = ty; i < 32; i += 8)
      tile[i][tx] = W[(size_t)(byy + i) * N + bxx + tx];
    __syncthreads();
    #pragma unroll
    for (int i = ty; i < 32; i += 8)
      Wt[(size_t)(bxx + i) * 1024 + byy + tx] = f2bf(tile[tx][i]);
    return;
  }
  int row = (b - 2560) * 4 + (threadIdx.x >> 6);
  gather_row(Aemb, Bemb, midx, X, counts, row, threadIdx.x & 63);
}

__global__ __launch_bounds__(512, 2)
void gemm8_kernel(const unsigned short* __restrict__ A,
                  const unsigned short* __restrict__ Bt,
                  const float* __restrict__ bias,
                  unsigned short* __restrict__ C) {
  extern __shared__ __align__(16) char smem[];
  gemm256_body(smem, threadIdx.x, (int)blockIdx.x, A, Bt, bias, C);
}

__global__ __launch_bounds__(512, 2)
void g3_kernel(const unsigned short* __restrict__ A,
               const unsigned short* __restrict__ Bt,
               const float* __restrict__ bias,
               const int* __restrict__ counts,
               float* __restrict__ Out) {
  extern __shared__ __align__(16) char smem[];
  gemm128f_body(smem, threadIdx.x, (int)blockIdx.x, A, Bt, bias, counts, Out);
}

extern "C" void kernel_launch(void* const* d_in, const int* in_sizes, int n_in,
                              void* d_out, int out_size, void* d_ws, size_t ws_size,
                              hipStream_t stream) {
  const float* a_emb = (const float*)d_in[0];
  const float* b_emb = (const float*)d_in[1];
  const int*   midx  = (const int*)d_in[2];
  const float* W_in  = (const float*)d_in[3];
  const float* b_in  = (const float*)d_in[4];
  const float* W_h   = (const float*)d_in[5];
  const float* b_h   = (const float*)d_in[6];
  const float* W_out = (const float*)d_in[7];
  const float* b_out = (const float*)d_in[8];
  char* ws = (char*)d_ws;

  unsigned short* X      = (unsigned short*)(ws);              // 16 MiB (reused as H2)
  unsigned short* H1     = (unsigned short*)(ws + 16777216);   // 16 MiB
  unsigned short* Wt_in  = (unsigned short*)(ws + 33554432);   //  2 MiB
  unsigned short* Wt_h   = (unsigned short*)(ws + 35651584);   //  2 MiB
  unsigned short* Wt_out = (unsigned short*)(ws + 37748736);   //  1 MiB
  int*            counts = (int*)(ws + 38797312);              // 32 KiB
  float*          outp   = (float*)d_out;

  (void)hipFuncSetAttribute((const void*)mega_kernel,
                            hipFuncAttributeMaxDynamicSharedMemorySize, 98304);
  (void)hipFuncSetAttribute((const void*)gemm8_kernel,
                            hipFuncAttributeMaxDynamicSharedMemorySize, 98304);

  void* kargs[] = { (void*)&a_emb, (void*)&b_emb, (void*)&midx,
                    (void*)&W_in, (void*)&W_h, (void*)&W_out,
                    (void*)&b_in, (void*)&b_h, (void*)&b_out,
                    (void*)&X, (void*)&H1, (void*)&Wt_in, (void*)&Wt_h,
                    (void*)&Wt_out, (void*)&counts, (void*)&outp };
  hipError_t e = hipLaunchCooperativeKernel((const void*)mega_kernel,
                                            dim3(256), dim3(512), kargs,
                                            98304u, stream);
  if (e != hipSuccess) {
    // fallback: identical math, separate launches (R5-proven structure)
    prep_kernel<<<4608, 256, 0, stream>>>(a_emb, b_emb, midx, W_in, W_h, W_out,
                                          X, counts, Wt_in, Wt_h, Wt_out);
    gemm8_kernel<<<256, 512, 98304, stream>>>(X,  Wt_in, b_in, H1);
    gemm8_kernel<<<256, 512, 98304, stream>>>(H1, Wt_h,  b_h,  X);
    g3_kernel<<<256, 512, 32768, stream>>>(X, Wt_out, b_out, counts, outp);
  }
}

// Round 9
// 113.324 us; speedup vs baseline: 2.0462x; 2.0462x over previous
//
#include <hip/hip_runtime.h>

#define DM 512
#define DI 1024
#define MM 16

typedef __attribute__((ext_vector_type(4))) float f32x4;
typedef __attribute__((ext_vector_type(8))) short short8;
typedef __attribute__((ext_vector_type(8))) unsigned short ushort8;

__device__ __forceinline__ unsigned short f2bf(float x) {
  union { float f; unsigned u; } c; c.f = x;
  unsigned r = (c.u + 0x7fffu + ((c.u >> 16) & 1u)) >> 16;
  return (unsigned short)r;
}

__device__ __forceinline__ void gload_lds16(const void* g, void* l) {
  __builtin_amdgcn_global_load_lds(
      (const __attribute__((address_space(1))) unsigned int*)g,
      (__attribute__((address_space(3))) unsigned int*)l, 16, 0, 0);
}

// ---- fused prep (R2-proven): 3 weight transposes + build_x in one launch
__device__ __forceinline__ void wt_tile(const float* __restrict__ W,
                                        unsigned short* __restrict__ Wt,
                                        int K, int N, int bx, int by,
                                        float (*tile)[33], int tx, int ty) {
  #pragma unroll
  for (int i = ty; i < 32; i += 8)
    tile[i][tx] = W[(size_t)(by + i) * N + bx + tx];
  __syncthreads();
  #pragma unroll
  for (int i = ty; i < 32; i += 8)
    Wt[(size_t)(bx + i) * K + by + tx] = f2bf(tile[tx][i]);
}

__global__ __launch_bounds__(256)
void prep_kernel(const float* __restrict__ Aemb,
                 const float* __restrict__ Bemb,
                 const int* __restrict__ midx,
                 const float* __restrict__ W_in,
                 const float* __restrict__ W_h,
                 const float* __restrict__ W_out,
                 unsigned short* __restrict__ X,
                 int* __restrict__ counts,
                 unsigned short* __restrict__ Wt_in,
                 unsigned short* __restrict__ Wt_h,
                 unsigned short* __restrict__ Wt_out) {
  __shared__ float tile[32][33];
  const int b = blockIdx.x;
  const int tx = threadIdx.x & 31, ty = threadIdx.x >> 5;
  if (b < 1024) {
    wt_tile(W_in, Wt_in, 1024, 1024, (b & 31) * 32, (b >> 5) * 32, tile, tx, ty);
    return;
  } else if (b < 2048) {
    int lb = b - 1024;
    wt_tile(W_h, Wt_h, 1024, 1024, (lb & 31) * 32, (lb >> 5) * 32, tile, tx, ty);
    return;
  } else if (b < 2560) {
    int lb = b - 2048;
    wt_tile(W_out, Wt_out, 1024, 512, (lb & 15) * 32, (lb >> 4) * 32, tile, tx, ty);
    return;
  }
  int row = __builtin_amdgcn_readfirstlane((b - 2560) * 4 + (threadIdx.x >> 6));
  int l = threadIdx.x & 63;
  float acc[8] = {0,0,0,0,0,0,0,0};
  int cnt = 0;
  const int* ip = midx + row * MM;
  #pragma unroll
  for (int m = 0; m < MM; ++m) {
    int id = ip[m];
    if (id >= 0) {
      ++cnt;
      const f32x4* p = (const f32x4*)(Bemb + (size_t)id * DM) + l * 2;
      f32x4 u = p[0], v = p[1];
      acc[0]+=u[0]; acc[1]+=u[1]; acc[2]+=u[2]; acc[3]+=u[3];
      acc[4]+=v[0]; acc[5]+=v[1]; acc[6]+=v[2]; acc[7]+=v[3];
    }
  }
  float inv = 1.0f / (float)(cnt > 0 ? cnt : 1);
  const f32x4* pa = (const f32x4*)(Aemb + (size_t)row * DM) + l * 2;
  f32x4 a0 = pa[0], a1 = pa[1];
  ushort8 va, vb;
  va[0]=f2bf(a0[0]); va[1]=f2bf(a0[1]); va[2]=f2bf(a0[2]); va[3]=f2bf(a0[3]);
  va[4]=f2bf(a1[0]); va[5]=f2bf(a1[1]); va[6]=f2bf(a1[2]); va[7]=f2bf(a1[3]);
  #pragma unroll
  for (int i = 0; i < 8; ++i) vb[i] = f2bf(acc[i] * inv);
  *(ushort8*)(X + (size_t)row * DI + l * 8) = va;
  *(ushort8*)(X + (size_t)row * DI + DM + l * 8) = vb;
  if (l == 0) counts[row] = cnt;
}

// ---- fine-grained 2-phase-per-K-tile GEMM (T2+T3+T4+T5), fixed shape:
// C[8192][1024] = relu(A[8192][1024] @ Bt[1024][1024]^T + bias), all bf16 in.
// BM=256 BN=128 BK=64, 8 waves (2Mx4N), per-wave 128x32 (8Mx2N frags).
// LDS: 2 bufs x (A 32KB + B 16KB) = 96KB. NT=16.
// Sub-tile staging ledger (per thread, 6 loads/tile: A-qm0 2, B 2, A-qm1 2):
//   G(t).ph0 reads {A-qm0,B} of buf(t), stages (t+1).qm1;  end: vmcnt(6)
//   G(t).ph1 reads {A-qm1} of buf(t),  stages (t+2).qm0+B; end: vmcnt(6)
//   (epilogue: 6 -> 2 -> 0; prologue: 12 issued, vmcnt(8))
__global__ __launch_bounds__(512, 2)
void gemm8_kernel(const unsigned short* __restrict__ A,
                  const unsigned short* __restrict__ Bt,
                  const float* __restrict__ bias,
                  unsigned short* __restrict__ C) {
  extern __shared__ __align__(16) char smem[];
  const int t = threadIdx.x;
  const int l = t & 63, w = t >> 6;
  const int wr = w >> 2, wc = w & 3;            // 2M x 4N waves
  const int f = blockIdx.y * gridDim.x + blockIdx.x;   // grid (8,32), 256 blocks
  const int swzid = (f & 7) * 32 + (f >> 3);    // chunked XCD swizzle
  const int bx = swzid & 7, by = swzid >> 3;
  const int blockM = by * 256, blockN = bx * 128;
  const unsigned short* __restrict__ Ab = A + (size_t)blockM * 1024;
  const unsigned short* __restrict__ Bb = Bt + (size_t)blockN * 1024;
  const int r = l & 15, ko = (l >> 4) * 8;
  const int swz = (r & 7) << 4;
  const int strow = t >> 3;                                  // 0..63 in chunk
  const int stcolh = ((((t & 7) * 16) ^ ((strow & 7) << 4)) >> 1); // elem col

  f32x4 acc[8][2];
  #pragma unroll
  for (int m = 0; m < 8; ++m) {
    acc[m][0] = (f32x4){0.f,0.f,0.f,0.f};
    acc[m][1] = (f32x4){0.f,0.f,0.f,0.f};
  }

#define ST_A(BASE, KT, CH)                                                    \
  gload_lds16(Ab + (size_t)((CH)*64 + strow) * 1024 + ((KT)<<6) + stcolh,     \
              smem + (BASE) + (CH)*8192 + t*16);
#define ST_B(BASE, KT, CB)                                                    \
  gload_lds16(Bb + (size_t)((CB)*64 + strow) * 1024 + ((KT)<<6) + stcolh,     \
              smem + (BASE) + 32768 + (CB)*8192 + t*16);
#define ST_QM0B(BASE, KT) { ST_A(BASE,KT,0) ST_A(BASE,KT,2) ST_B(BASE,KT,0) ST_B(BASE,KT,1) }
#define ST_QM1(BASE, KT)  { ST_A(BASE,KT,1) ST_A(BASE,KT,3) }

#define WAIT_VM(N) { asm volatile("s_waitcnt vmcnt(" #N ")" ::: "memory");    \
                     __builtin_amdgcn_sched_barrier(0); }
#define WAIT_LGKM() { asm volatile("s_waitcnt lgkmcnt(0)" ::: "memory");      \
                      __builtin_amdgcn_sched_barrier(0); }
#define BAR() { __builtin_amdgcn_s_barrier();                                 \
                __builtin_amdgcn_sched_barrier(0); }

  short8 aF[4][2], bF[2][2];

#define LDA(MF4, KK, BASE, QM)                                                \
  aF[MF4][KK] = *(const short8*)(smem + (BASE) +                              \
      ((((wr*128 + ((QM)*4+(MF4))*16 + r) * 128) + ((KK)*32 + ko)*2) ^ swz));
#define LDB(NF, KK, BASE)                                                     \
  bF[NF][KK] = *(const short8*)(smem + (BASE) + 32768 +                       \
      ((((wc*32 + (NF)*16 + r) * 128) + ((KK)*32 + ko)*2) ^ swz));

#define MFMA16(QM)                                                            \
  __builtin_amdgcn_s_setprio(1);                                              \
  _Pragma("unroll") for (int mf4 = 0; mf4 < 4; ++mf4)                         \
    _Pragma("unroll") for (int kk = 0; kk < 2; ++kk)                          \
      _Pragma("unroll") for (int nf = 0; nf < 2; ++nf)                        \
        acc[(QM)*4+mf4][nf] = __builtin_amdgcn_mfma_f32_16x16x32_bf16(        \
            aF[mf4][kk], bF[nf][kk], acc[(QM)*4+mf4][nf], 0, 0, 0);           \
  __builtin_amdgcn_s_setprio(0);

#define DS_A(BASE, QM) _Pragma("unroll")                                      \
  for (int mf4 = 0; mf4 < 4; ++mf4) { LDA(mf4,0,BASE,QM) LDA(mf4,1,BASE,QM) }
#define DS_B(BASE) { LDB(0,0,BASE) LDB(0,1,BASE) LDB(1,0,BASE) LDB(1,1,BASE) }

  // ---- prologue: tiles 0,1 fully staged (12 loads; oldest 4 = t0 qm0+B)
  ST_QM0B(0, 0) ST_QM1(0, 0)
  ST_QM0B(49152, 1) ST_QM1(49152, 1)
  WAIT_VM(8) BAR()

  // ---- G(0)
  { DS_A(0,0) DS_B(0)
    WAIT_LGKM() MFMA16(0)
    WAIT_VM(6) BAR() }
  { DS_A(0,1)
    ST_QM0B(0, 2)                 // t2 qm0+B -> buf0 (freed by ph0 barrier)
    WAIT_LGKM() MFMA16(1)
    WAIT_VM(6) BAR() }

  // ---- steady: kt = 1..13
  #pragma unroll 1
  for (int kt = 1; kt <= 13; ++kt) {
    const int bo = (kt & 1) * 49152;
    const int bo2 = bo ^ 49152;
    { DS_A(bo,0) DS_B(bo)
      ST_QM1(bo2, kt+1)           // (kt+1).qm1 -> other buf (qm1 freed @ G(kt-1).ph1)
      WAIT_LGKM() MFMA16(0)
      WAIT_VM(6) BAR() }
    { DS_A(bo,1)
      ST_QM0B(bo, kt+2)           // (kt+2).qm0+B -> this buf (freed @ ph0)
      WAIT_LGKM() MFMA16(1)
      WAIT_VM(6) BAR() }
  }

  // ---- G(14) (buf0)
  { DS_A(0,0) DS_B(0)
    ST_QM1(49152, 15)
    WAIT_LGKM() MFMA16(0)
    WAIT_VM(6) BAR() }
  { DS_A(0,1)
    WAIT_LGKM() MFMA16(1)
    WAIT_VM(2) BAR() }
  // ---- G(15) (buf1)
  { DS_A(49152,0) DS_B(49152)
    WAIT_LGKM() MFMA16(0)
    WAIT_VM(0) BAR() }
  { DS_A(49152,1)
    WAIT_LGKM() MFMA16(1) }

#undef ST_A
#undef ST_B
#undef ST_QM0B
#undef ST_QM1
#undef WAIT_VM
#undef WAIT_LGKM
#undef BAR
#undef LDA
#undef LDB
#undef MFMA16
#undef DS_A
#undef DS_B

  // ---- epilogue: bias + relu, C/D map col=lane&15, row=(lane>>4)*4+reg
  float bn2[2];
  bn2[0] = bias[blockN + wc * 32 + r];
  bn2[1] = bias[blockN + wc * 32 + 16 + r];
  const int rowBase = blockM + wr * 128 + (l >> 4) * 4;
  #pragma unroll
  for (int mf = 0; mf < 8; ++mf)
    #pragma unroll
    for (int j = 0; j < 4; ++j) {
      int grow = rowBase + mf * 16 + j;
      #pragma unroll
      for (int nf = 0; nf < 2; ++nf) {
        float v = acc[mf][nf][j] + bn2[nf];
        v = v > 0.f ? v : 0.f;
        C[(size_t)grow * 1024 + blockN + wc * 32 + nf * 16 + r] = f2bf(v);
      }
    }
}

// ---- m97-structure GEMM (proven) for the final layer (N=512, counts mask, f32 out)
template<int RELU, int FINAL>
__global__ __launch_bounds__(256, 2)
void gemm_kernel(const unsigned short* __restrict__ A, int lda,
                 const unsigned short* __restrict__ Bt, int ldb, int Kext,
                 const float* __restrict__ bias,
                 unsigned short* __restrict__ Cb,
                 float* __restrict__ Cf,
                 const int* __restrict__ counts,
                 int N) {
  __shared__ __align__(16) unsigned short As[128 * 64];
  __shared__ __align__(16) unsigned short Bs[128 * 64];
  const int t = threadIdx.x;
  const int l = t & 63, w = t >> 6;
  const int wr = w >> 1, wc = w & 1;

  const int nwg = gridDim.x * gridDim.y;
  const int wg = blockIdx.y * gridDim.x + blockIdx.x;
  const int swzid = (wg & 7) * (nwg >> 3) + (wg >> 3);
  const int bx = swzid % gridDim.x, by = swzid / gridDim.x;

  const int blockM = by * 128, blockN = bx * 128;
  const unsigned short* Ab = A + (size_t)blockM * lda;
  const unsigned short* Bb = Bt + (size_t)blockN * ldb;

  f32x4 acc[4][4];
  #pragma unroll
  for (int m = 0; m < 4; ++m)
    #pragma unroll
    for (int n = 0; n < 4; ++n) acc[m][n] = (f32x4){0.f, 0.f, 0.f, 0.f};

  int so_row[4], so_col[4];
  #pragma unroll
  for (int c = 0; c < 4; ++c) {
    int o = c * 4096 + t * 16;
    int row = o >> 7;
    int cb = (o & 127) ^ ((row & 7) << 4);
    so_row[c] = row; so_col[c] = cb >> 1;
  }

  const int r = l & 15, ko = (l >> 4) * 8;
  const int swz = (r & 7) << 4;
  const char* Ac = (const char*)As;
  const char* Bc = (const char*)Bs;
  const int NT = Kext >> 6;

  #pragma unroll
  for (int c = 0; c < 4; ++c) {
    gload_lds16(Ab + (size_t)so_row[c] * lda + so_col[c], (char*)As + c * 4096 + w * 1024);
    gload_lds16(Bb + (size_t)so_row[c] * ldb + so_col[c], (char*)Bs + c * 4096 + w * 1024);
  }

  for (int kt = 0; kt < NT; ++kt) {
    __syncthreads();
    #pragma unroll
    for (int kk = 0; kk < 64; kk += 32) {
      short8 aF[4], bF[4];
      #pragma unroll
      for (int m = 0; m < 4; ++m)
        aF[m] = *(const short8*)(Ac + (((wr * 64 + m * 16 + r) * 128 + (kk + ko) * 2) ^ swz));
      #pragma unroll
      for (int n = 0; n < 4; ++n)
        bF[n] = *(const short8*)(Bc + (((wc * 64 + n * 16 + r) * 128 + (kk + ko) * 2) ^ swz));
      #pragma unroll
      for (int m = 0; m < 4; ++m)
        #pragma unroll
        for (int n = 0; n < 4; ++n)
          acc[m][n] = __builtin_amdgcn_mfma_f32_16x16x32_bf16(aF[m], bF[n], acc[m][n], 0, 0, 0);
    }
    __syncthreads();
    if (kt + 1 < NT) {
      int k0 = (kt + 1) << 6;
      #pragma unroll
      for (int c = 0; c < 4; ++c) {
        gload_lds16(Ab + (size_t)so_row[c] * lda + k0 + so_col[c], (char*)As + c * 4096 + w * 1024);
        gload_lds16(Bb + (size_t)so_row[c] * ldb + k0 + so_col[c], (char*)Bs + c * 4096 + w * 1024);
      }
    }
  }

  float bn[4];
  #pragma unroll
  for (int n = 0; n < 4; ++n) bn[n] = bias[blockN + wc * 64 + n * 16 + r];
  const int rowBase = blockM + wr * 64 + (l >> 4) * 4;
  #pragma unroll
  for (int m = 0; m < 4; ++m) {
    #pragma unroll
    for (int jj = 0; jj < 4; ++jj) {
      int grow = rowBase + m * 16 + jj;
      if (FINAL) {
        float cm = (counts[grow] > 0) ? 1.0f : 0.0f;
        #pragma unroll
        for (int n = 0; n < 4; ++n) {
          float v = (acc[m][n][jj] + bn[n]) * cm;
          Cf[(size_t)grow * N + blockN + wc * 64 + n * 16 + r] = v;
        }
      } else {
        #pragma unroll
        for (int n = 0; n < 4; ++n) {
          float v = acc[m][n][jj] + bn[n];
          if (RELU) v = v > 0.f ? v : 0.f;
          Cb[(size_t)grow * N + blockN + wc * 64 + n * 16 + r] = f2bf(v);
        }
      }
    }
  }
}

extern "C" void kernel_launch(void* const* d_in, const int* in_sizes, int n_in,
                              void* d_out, int out_size, void* d_ws, size_t ws_size,
                              hipStream_t stream) {
  const float* a_emb = (const float*)d_in[0];
  const float* b_emb = (const float*)d_in[1];
  const int*   midx  = (const int*)d_in[2];
  const float* W_in  = (const float*)d_in[3];
  const float* b_in  = (const float*)d_in[4];
  const float* W_h   = (const float*)d_in[5];
  const float* b_h   = (const float*)d_in[6];
  const float* W_out = (const float*)d_in[7];
  const float* b_out = (const float*)d_in[8];
  char* ws = (char*)d_ws;

  unsigned short* X      = (unsigned short*)(ws);              // 16 MiB (reused as H2)
  unsigned short* H1     = (unsigned short*)(ws + 16777216);   // 16 MiB
  unsigned short* Wt_in  = (unsigned short*)(ws + 33554432);   //  2 MiB
  unsigned short* Wt_h   = (unsigned short*)(ws + 35651584);   //  2 MiB
  unsigned short* Wt_out = (unsigned short*)(ws + 37748736);   //  1 MiB
  int*            counts = (int*)(ws + 38797312);              // 32 KiB

  (void)hipFuncSetAttribute((const void*)gemm8_kernel,
                            hipFuncAttributeMaxDynamicSharedMemorySize, 98304);

  prep_kernel<<<4608, 256, 0, stream>>>(a_emb, b_emb, midx, W_in, W_h, W_out,
                                        X, counts, Wt_in, Wt_h, Wt_out);

  gemm8_kernel<<<dim3(8, 32), 512, 98304, stream>>>(X,  Wt_in, b_in, H1);
  gemm8_kernel<<<dim3(8, 32), 512, 98304, stream>>>(H1, Wt_h,  b_h,  X);
  gemm_kernel<0, 1><<<dim3(4, 64), 256, 0, stream>>>(X, 1024, Wt_out, 1024, 1024,
                                                     b_out, nullptr, (float*)d_out, counts, 512);
}

// Round 11
// 110.785 us; speedup vs baseline: 2.0931x; 1.0229x over previous
//
#include <hip/hip_runtime.h>

#define DM 512
#define DI 1024
#define MM 16

typedef __attribute__((ext_vector_type(4))) float f32x4;
typedef __attribute__((ext_vector_type(8))) short short8;
typedef __attribute__((ext_vector_type(8))) unsigned short ushort8;

__device__ __forceinline__ unsigned short f2bf(float x) {
  union { float f; unsigned u; } c; c.f = x;
  unsigned r = (c.u + 0x7fffu + ((c.u >> 16) & 1u)) >> 16;
  return (unsigned short)r;
}

__device__ __forceinline__ void gload_lds16(const void* g, void* l) {
  __builtin_amdgcn_global_load_lds(
      (const __attribute__((address_space(1))) unsigned int*)g,
      (__attribute__((address_space(3))) unsigned int*)l, 16, 0, 0);
}

// ---- fused prep: 3 weight transposes + build_x in one launch.
// Gather is BRANCHLESS (safe_idx + mask, reference's own pattern) with
// 4-match load groups -> 8 independent 16B loads in flight per wave
// (old version: divergent-free but branch-guarded loads, ~2-3 deep).
__device__ __forceinline__ void wt_tile(const float* __restrict__ W,
                                        unsigned short* __restrict__ Wt,
                                        int K, int N, int bx, int by,
                                        float (*tile)[33], int tx, int ty) {
  #pragma unroll
  for (int i = ty; i < 32; i += 8)
    tile[i][tx] = W[(size_t)(by + i) * N + bx + tx];
  __syncthreads();
  #pragma unroll
  for (int i = ty; i < 32; i += 8)
    Wt[(size_t)(bx + i) * K + by + tx] = f2bf(tile[tx][i]);
}

__global__ __launch_bounds__(256)
void prep_kernel(const float* __restrict__ Aemb,
                 const float* __restrict__ Bemb,
                 const int* __restrict__ midx,
                 const float* __restrict__ W_in,
                 const float* __restrict__ W_h,
                 const float* __restrict__ W_out,
                 unsigned short* __restrict__ X,
                 int* __restrict__ counts,
                 unsigned short* __restrict__ Wt_in,
                 unsigned short* __restrict__ Wt_h,
                 unsigned short* __restrict__ Wt_out) {
  __shared__ float tile[32][33];
  const int b = blockIdx.x;
  const int tx = threadIdx.x & 31, ty = threadIdx.x >> 5;
  if (b < 1024) {
    wt_tile(W_in, Wt_in, 1024, 1024, (b & 31) * 32, (b >> 5) * 32, tile, tx, ty);
    return;
  } else if (b < 2048) {
    int lb = b - 1024;
    wt_tile(W_h, Wt_h, 1024, 1024, (lb & 31) * 32, (lb >> 5) * 32, tile, tx, ty);
    return;
  } else if (b < 2560) {
    int lb = b - 2048;
    wt_tile(W_out, Wt_out, 1024, 512, (lb & 15) * 32, (lb >> 4) * 32, tile, tx, ty);
    return;
  }
  // ---- branchless gather: one wave per row
  int row = (b - 2560) * 4 + (threadIdx.x >> 6);
  int l = threadIdx.x & 63;
  const int* ip = midx + row * MM;
  float acc[8] = {0,0,0,0,0,0,0,0};
  int cnt = 0;
  #pragma unroll
  for (int g = 0; g < 4; ++g) {
    // group of 4 matches: compute masks/safe ids, issue all 8 loads, then add
    float s[4];
    const f32x4* p[4];
    #pragma unroll
    for (int j = 0; j < 4; ++j) {
      int id = ip[g * 4 + j];
      s[j] = (id >= 0) ? 1.0f : 0.0f;
      cnt += (id >= 0) ? 1 : 0;
      p[j] = (const f32x4*)(Bemb + (size_t)(id >= 0 ? id : 0) * DM) + l * 2;
    }
    f32x4 u[4], v[4];
    #pragma unroll
    for (int j = 0; j < 4; ++j) { u[j] = p[j][0]; v[j] = p[j][1]; }
    #pragma unroll
    for (int j = 0; j < 4; ++j) {
      acc[0] += s[j]*u[j][0]; acc[1] += s[j]*u[j][1];
      acc[2] += s[j]*u[j][2]; acc[3] += s[j]*u[j][3];
      acc[4] += s[j]*v[j][0]; acc[5] += s[j]*v[j][1];
      acc[6] += s[j]*v[j][2]; acc[7] += s[j]*v[j][3];
    }
  }
  float inv = 1.0f / (float)(cnt > 0 ? cnt : 1);
  const f32x4* pa = (const f32x4*)(Aemb + (size_t)row * DM) + l * 2;
  f32x4 a0 = pa[0], a1 = pa[1];
  ushort8 va, vb;
  va[0]=f2bf(a0[0]); va[1]=f2bf(a0[1]); va[2]=f2bf(a0[2]); va[3]=f2bf(a0[3]);
  va[4]=f2bf(a1[0]); va[5]=f2bf(a1[1]); va[6]=f2bf(a1[2]); va[7]=f2bf(a1[3]);
  #pragma unroll
  for (int i = 0; i < 8; ++i) vb[i] = f2bf(acc[i] * inv);
  *(ushort8*)(X + (size_t)row * DI + l * 8) = va;
  *(ushort8*)(X + (size_t)row * DI + DM + l * 8) = vb;
  if (l == 0) counts[row] = cnt;
}

// ---- fine-grained 2-phase-per-K-tile GEMM (T2+T3+T4+T5), fixed shape:
// C[8192][1024] = relu(A[8192][1024] @ Bt[1024][1024]^T + bias), all bf16 in.
// BM=256 BN=128 BK=64, 8 waves (2Mx4N), per-wave 128x32 (8Mx2N frags).
// LDS: 2 bufs x (A 32KB + B 16KB) = 96KB. NT=16.  (R5/R8-proven verbatim)
__global__ __launch_bounds__(512, 2)
void gemm8_kernel(const unsigned short* __restrict__ A,
                  const unsigned short* __restrict__ Bt,
                  const float* __restrict__ bias,
                  unsigned short* __restrict__ C) {
  extern __shared__ __align__(16) char smem[];
  const int t = threadIdx.x;
  const int l = t & 63, w = t >> 6;
  const int wr = w >> 2, wc = w & 3;            // 2M x 4N waves
  const int f = blockIdx.y * gridDim.x + blockIdx.x;   // grid (8,32), 256 blocks
  const int swzid = (f & 7) * 32 + (f >> 3);    // chunked XCD swizzle
  const int bx = swzid & 7, by = swzid >> 3;
  const int blockM = by * 256, blockN = bx * 128;
  const unsigned short* __restrict__ Ab = A + (size_t)blockM * 1024;
  const unsigned short* __restrict__ Bb = Bt + (size_t)blockN * 1024;
  const int r = l & 15, ko = (l >> 4) * 8;
  const int swz = (r & 7) << 4;
  const int strow = t >> 3;                                  // 0..63 in chunk
  const int stcolh = ((((t & 7) * 16) ^ ((strow & 7) << 4)) >> 1); // elem col

  f32x4 acc[8][2];
  #pragma unroll
  for (int m = 0; m < 8; ++m) {
    acc[m][0] = (f32x4){0.f,0.f,0.f,0.f};
    acc[m][1] = (f32x4){0.f,0.f,0.f,0.f};
  }

#define ST_A(BASE, KT, CH)                                                    \
  gload_lds16(Ab + (size_t)((CH)*64 + strow) * 1024 + ((KT)<<6) + stcolh,     \
              smem + (BASE) + (CH)*8192 + t*16);
#define ST_B(BASE, KT, CB)                                                    \
  gload_lds16(Bb + (size_t)((CB)*64 + strow) * 1024 + ((KT)<<6) + stcolh,     \
              smem + (BASE) + 32768 + (CB)*8192 + t*16);
#define ST_QM0B(BASE, KT) { ST_A(BASE,KT,0) ST_A(BASE,KT,2) ST_B(BASE,KT,0) ST_B(BASE,KT,1) }
#define ST_QM1(BASE, KT)  { ST_A(BASE,KT,1) ST_A(BASE,KT,3) }

#define WAIT_VM(N) { asm volatile("s_waitcnt vmcnt(" #N ")" ::: "memory");    \
                     __builtin_amdgcn_sched_barrier(0); }
#define WAIT_LGKM() { asm volatile("s_waitcnt lgkmcnt(0)" ::: "memory");      \
                      __builtin_amdgcn_sched_barrier(0); }
#define BAR() { __builtin_amdgcn_s_barrier();                                 \
                __builtin_amdgcn_sched_barrier(0); }

  short8 aF[4][2], bF[2][2];

#define LDA(MF4, KK, BASE, QM)                                                \
  aF[MF4][KK] = *(const short8*)(smem + (BASE) +                              \
      ((((wr*128 + ((QM)*4+(MF4))*16 + r) * 128) + ((KK)*32 + ko)*2) ^ swz));
#define LDB(NF, KK, BASE)                                                     \
  bF[NF][KK] = *(const short8*)(smem + (BASE) + 32768 +                       \
      ((((wc*32 + (NF)*16 + r) * 128) + ((KK)*32 + ko)*2) ^ swz));

#define MFMA16(QM)                                                            \
  __builtin_amdgcn_s_setprio(1);                                              \
  _Pragma("unroll") for (int mf4 = 0; mf4 < 4; ++mf4)                         \
    _Pragma("unroll") for (int kk = 0; kk < 2; ++kk)                          \
      _Pragma("unroll") for (int nf = 0; nf < 2; ++nf)                        \
        acc[(QM)*4+mf4][nf] = __builtin_amdgcn_mfma_f32_16x16x32_bf16(        \
            aF[mf4][kk], bF[nf][kk], acc[(QM)*4+mf4][nf], 0, 0, 0);           \
  __builtin_amdgcn_s_setprio(0);

#define DS_A(BASE, QM) _Pragma("unroll")                                      \
  for (int mf4 = 0; mf4 < 4; ++mf4) { LDA(mf4,0,BASE,QM) LDA(mf4,1,BASE,QM) }
#define DS_B(BASE) { LDB(0,0,BASE) LDB(0,1,BASE) LDB(1,0,BASE) LDB(1,1,BASE) }

  // ---- prologue: tiles 0,1 fully staged (12 loads; oldest 4 = t0 qm0+B)
  ST_QM0B(0, 0) ST_QM1(0, 0)
  ST_QM0B(49152, 1) ST_QM1(49152, 1)
  WAIT_VM(8) BAR()

  // ---- G(0)
  { DS_A(0,0) DS_B(0)
    WAIT_LGKM() MFMA16(0)
    WAIT_VM(6) BAR() }
  { DS_A(0,1)
    ST_QM0B(0, 2)                 // t2 qm0+B -> buf0 (freed by ph0 barrier)
    WAIT_LGKM() MFMA16(1)
    WAIT_VM(6) BAR() }

  // ---- steady: kt = 1..13
  #pragma unroll 1
  for (int kt = 1; kt <= 13; ++kt) {
    const int bo = (kt & 1) * 49152;
    const int bo2 = bo ^ 49152;
    { DS_A(bo,0) DS_B(bo)
      ST_QM1(bo2, kt+1)           // (kt+1).qm1 -> other buf (qm1 freed @ G(kt-1).ph1)
      WAIT_LGKM() MFMA16(0)
      WAIT_VM(6) BAR() }
    { DS_A(bo,1)
      ST_QM0B(bo, kt+2)           // (kt+2).qm0+B -> this buf (freed @ ph0)
      WAIT_LGKM() MFMA16(1)
      WAIT_VM(6) BAR() }
  }

  // ---- G(14) (buf0)
  { DS_A(0,0) DS_B(0)
    ST_QM1(49152, 15)
    WAIT_LGKM() MFMA16(0)
    WAIT_VM(6) BAR() }
  { DS_A(0,1)
    WAIT_LGKM() MFMA16(1)
    WAIT_VM(2) BAR() }
  // ---- G(15) (buf1)
  { DS_A(49152,0) DS_B(49152)
    WAIT_LGKM() MFMA16(0)
    WAIT_VM(0) BAR() }
  { DS_A(49152,1)
    WAIT_LGKM() MFMA16(1) }

#undef ST_A
#undef ST_B
#undef ST_QM0B
#undef ST_QM1
#undef WAIT_VM
#undef WAIT_LGKM
#undef BAR
#undef LDA
#undef LDB
#undef MFMA16
#undef DS_A
#undef DS_B

  // ---- epilogue: bias + relu, C/D map col=lane&15, row=(lane>>4)*4+reg
  float bn2[2];
  bn2[0] = bias[blockN + wc * 32 + r];
  bn2[1] = bias[blockN + wc * 32 + 16 + r];
  const int rowBase = blockM + wr * 128 + (l >> 4) * 4;
  #pragma unroll
  for (int mf = 0; mf < 8; ++mf)
    #pragma unroll
    for (int j = 0; j < 4; ++j) {
      int grow = rowBase + mf * 16 + j;
      #pragma unroll
      for (int nf = 0; nf < 2; ++nf) {
        float v = acc[mf][nf][j] + bn2[nf];
        v = v > 0.f ? v : 0.f;
        C[(size_t)grow * 1024 + blockN + wc * 32 + nf * 16 + r] = f2bf(v);
      }
    }
}

// ---- m97-structure GEMM (proven) for the final layer (N=512, counts mask, f32 out)
template<int RELU, int FINAL>
__global__ __launch_bounds__(256, 2)
void gemm_kernel(const unsigned short* __restrict__ A, int lda,
                 const unsigned short* __restrict__ Bt, int ldb, int Kext,
                 const float* __restrict__ bias,
                 unsigned short* __restrict__ Cb,
                 float* __restrict__ Cf,
                 const int* __restrict__ counts,
                 int N) {
  __shared__ __align__(16) unsigned short As[128 * 64];
  __shared__ __align__(16) unsigned short Bs[128 * 64];
  const int t = threadIdx.x;
  const int l = t & 63, w = t >> 6;
  const int wr = w >> 1, wc = w & 1;

  const int nwg = gridDim.x * gridDim.y;
  const int wg = blockIdx.y * gridDim.x + blockIdx.x;
  const int swzid = (wg & 7) * (nwg >> 3) + (wg >> 3);
  const int bx = swzid % gridDim.x, by = swzid / gridDim.x;

  const int blockM = by * 128, blockN = bx * 128;
  const unsigned short* Ab = A + (size_t)blockM * lda;
  const unsigned short* Bb = Bt + (size_t)blockN * ldb;

  f32x4 acc[4][4];
  #pragma unroll
  for (int m = 0; m < 4; ++m)
    #pragma unroll
    for (int n = 0; n < 4; ++n) acc[m][n] = (f32x4){0.f, 0.f, 0.f, 0.f};

  int so_row[4], so_col[4];
  #pragma unroll
  for (int c = 0; c < 4; ++c) {
    int o = c * 4096 + t * 16;
    int row = o >> 7;
    int cb = (o & 127) ^ ((row & 7) << 4);
    so_row[c] = row; so_col[c] = cb >> 1;
  }

  const int r = l & 15, ko = (l >> 4) * 8;
  const int swz = (r & 7) << 4;
  const char* Ac = (const char*)As;
  const char* Bc = (const char*)Bs;
  const int NT = Kext >> 6;

  #pragma unroll
  for (int c = 0; c < 4; ++c) {
    gload_lds16(Ab + (size_t)so_row[c] * lda + so_col[c], (char*)As + c * 4096 + w * 1024);
    gload_lds16(Bb + (size_t)so_row[c] * ldb + so_col[c], (char*)Bs + c * 4096 + w * 1024);
  }

  for (int kt = 0; kt < NT; ++kt) {
    __syncthreads();
    #pragma unroll
    for (int kk = 0; kk < 64; kk += 32) {
      short8 aF[4], bF[4];
      #pragma unroll
      for (int m = 0; m < 4; ++m)
        aF[m] = *(const short8*)(Ac + (((wr * 64 + m * 16 + r) * 128 + (kk + ko) * 2) ^ swz));
      #pragma unroll
      for (int n = 0; n < 4; ++n)
        bF[n] = *(const short8*)(Bc + (((wc * 64 + n * 16 + r) * 128 + (kk + ko) * 2) ^ swz));
      #pragma unroll
      for (int m = 0; m < 4; ++m)
        #pragma unroll
        for (int n = 0; n < 4; ++n)
          acc[m][n] = __builtin_amdgcn_mfma_f32_16x16x32_bf16(aF[m], bF[n], acc[m][n], 0, 0, 0);
    }
    __syncthreads();
    if (kt + 1 < NT) {
      int k0 = (kt + 1) << 6;
      #pragma unroll
      for (int c = 0; c < 4; ++c) {
        gload_lds16(Ab + (size_t)so_row[c] * lda + k0 + so_col[c], (char*)As + c * 4096 + w * 1024);
        gload_lds16(Bb + (size_t)so_row[c] * ldb + k0 + so_col[c], (char*)Bs + c * 4096 + w * 1024);
      }
    }
  }

  float bn[4];
  #pragma unroll
  for (int n = 0; n < 4; ++n) bn[n] = bias[blockN + wc * 64 + n * 16 + r];
  const int rowBase = blockM + wr * 64 + (l >> 4) * 4;
  #pragma unroll
  for (int m = 0; m < 4; ++m) {
    #pragma unroll
    for (int jj = 0; jj < 4; ++jj) {
      int grow = rowBase + m * 16 + jj;
      if (FINAL) {
        float cm = (counts[grow] > 0) ? 1.0f : 0.0f;
        #pragma unroll
        for (int n = 0; n < 4; ++n) {
          float v = (acc[m][n][jj] + bn[n]) * cm;
          Cf[(size_t)grow * N + blockN + wc * 64 + n * 16 + r] = v;
        }
      } else {
        #pragma unroll
        for (int n = 0; n < 4; ++n) {
          float v = acc[m][n][jj] + bn[n];
          if (RELU) v = v > 0.f ? v : 0.f;
          Cb[(size_t)grow * N + blockN + wc * 64 + n * 16 + r] = f2bf(v);
        }
      }
    }
  }
}

extern "C" void kernel_launch(void* const* d_in, const int* in_sizes, int n_in,
                              void* d_out, int out_size, void* d_ws, size_t ws_size,
                              hipStream_t stream) {
  const float* a_emb = (const float*)d_in[0];
  const float* b_emb = (const float*)d_in[1];
  const int*   midx  = (const int*)d_in[2];
  const float* W_in  = (const float*)d_in[3];
  const float* b_in  = (const float*)d_in[4];
  const float* W_h   = (const float*)d_in[5];
  const float* b_h   = (const float*)d_in[6];
  const float* W_out = (const float*)d_in[7];
  const float* b_out = (const float*)d_in[8];
  char* ws = (char*)d_ws;

  unsigned short* X      = (unsigned short*)(ws);              // 16 MiB (reused as H2)
  unsigned short* H1     = (unsigned short*)(ws + 16777216);   // 16 MiB
  unsigned short* Wt_in  = (unsigned short*)(ws + 33554432);   //  2 MiB
  unsigned short* Wt_h   = (unsigned short*)(ws + 35651584);   //  2 MiB
  unsigned short* Wt_out = (unsigned short*)(ws + 37748736);   //  1 MiB
  int*            counts = (int*)(ws + 38797312);              // 32 KiB

  (void)hipFuncSetAttribute((const void*)gemm8_kernel,
                            hipFuncAttributeMaxDynamicSharedMemorySize, 98304);

  prep_kernel<<<4608, 256, 0, stream>>>(a_emb, b_emb, midx, W_in, W_h, W_out,
                                        X, counts, Wt_in, Wt_h, Wt_out);

  gemm8_kernel<<<dim3(8, 32), 512, 98304, stream>>>(X,  Wt_in, b_in, H1);
  gemm8_kernel<<<dim3(8, 32), 512, 98304, stream>>>(H1, Wt_h,  b_h,  X);
  gemm_kernel<0, 1><<<dim3(4, 64), 256, 0, stream>>>(X, 1024, Wt_out, 1024, 1024,
                                                     b_out, nullptr, (float*)d_out, counts, 512);
}